// Round 2
// baseline (43157.578 us; speedup 1.0000x reference)
//
#include <hip/hip_runtime.h>

// MultiRegionRNN T=512,B=128,D_IN=64,N=512,D_OUT=2,ALPHA=0.1
// Persistent cooperative kernel, 511 steps.
// Round-2 fix: NO agent fences in steady state (they invalidate per-XCD L2 and
// forced a 17MB/step weight refetch -> 38ms latency-bound). Cross-XCD r exchange
// via write-through atomic stores + L2-bypass atomic loads; weights/XT stay hot
// in L2 and are read with normal cached loads.
//   g_Wcat[R][k][n] : k-major weights [rec 512 | inter 512 | (A) input 64]
//   g_XT[t][d][b]   : transposed input
//   g_r[buf][R][n][b]: ping-pong rates (coherent traffic only)
// WG = (region, 16 cols, 64 batch), 512 thr = 8 waves K-split (2 waves/SIMD TLP).

#define NWG   192
#define NTHR  512
#define GTHREADS (NWG * NTHR)

__device__ float g_Wcat[3][1088][512];   // 6.7 MB, L2-resident after step 1
__device__ float g_XT[512][64][128];     // 16.8 MB streamed
__device__ float g_r[2][3][512][128];    // ping-pong rates, coherent path

__device__ __forceinline__ float fast_tanh(float x) {
    float e = __expf(2.0f * x);
    return 1.0f - 2.0f / (e + 1.0f);
}
// L2-bypass coherent load (sc0+sc1): reads coherence point, no invalidate needed
__device__ __forceinline__ float ld_cg(const float* p) {
    return __hip_atomic_load(p, __ATOMIC_RELAXED, __HIP_MEMORY_SCOPE_AGENT);
}
// write-through coherent store: value lands at coherence point, vmcnt-tracked
__device__ __forceinline__ void st_wt(float* p, float v) {
    __hip_atomic_store(p, v, __ATOMIC_RELAXED, __HIP_MEMORY_SCOPE_AGENT);
}
__device__ __forceinline__ void st_wt2(float* p, float2 v) {
    union { float2 f; unsigned long long u; } cv; cv.f = v;
    __hip_atomic_store((unsigned long long*)p, cv.u, __ATOMIC_RELAXED, __HIP_MEMORY_SCOPE_AGENT);
}
__device__ __forceinline__ unsigned ld_u32(const unsigned* p) {
    return __hip_atomic_load(p, __ATOMIC_RELAXED, __HIP_MEMORY_SCOPE_AGENT);
}

// counters at ws[i*64] (256B apart), epoch flag at ws[1024]
__device__ __forceinline__ void grid_barrier(unsigned* ws, int wg, unsigned epoch,
                                             bool full_fence) {
    asm volatile("s_waitcnt vmcnt(0)" ::: "memory");  // drain write-through r stores
    __syncthreads();
    if (threadIdx.x == 0) {
        if (full_fence) __builtin_amdgcn_fence(__ATOMIC_RELEASE, "agent");
        __hip_atomic_fetch_add(&ws[(wg & 15) * 64], 1u, __ATOMIC_RELAXED,
                               __HIP_MEMORY_SCOPE_AGENT);
        if (wg == 0) {
            const unsigned tgt = (unsigned)NWG * epoch;
            for (;;) {
                unsigned s = 0;
                #pragma unroll
                for (int i = 0; i < 16; ++i) s += ld_u32(&ws[i * 64]);
                if (s >= tgt) break;
                __builtin_amdgcn_s_sleep(2);
            }
            __hip_atomic_store(&ws[1024], epoch, __ATOMIC_RELAXED, __HIP_MEMORY_SCOPE_AGENT);
        } else {
            while ((int)(ld_u32(&ws[1024]) - epoch) < 0) __builtin_amdgcn_s_sleep(2);
        }
        if (full_fence) __builtin_amdgcn_fence(__ATOMIC_ACQUIRE, "agent");
    }
    __syncthreads();
}

// 16 FMAs with a wave-uniform weight row (vector loads -> L2-hit broadcast)
__device__ __forceinline__ void fma16(float acc[16], const float* __restrict__ wrow,
                                      float rv) {
    const float4* w4 = (const float4*)wrow;
    float4 w0 = w4[0], w1 = w4[1], w2 = w4[2], w3 = w4[3];
    acc[0]  = fmaf(w0.x, rv, acc[0]);  acc[1]  = fmaf(w0.y, rv, acc[1]);
    acc[2]  = fmaf(w0.z, rv, acc[2]);  acc[3]  = fmaf(w0.w, rv, acc[3]);
    acc[4]  = fmaf(w1.x, rv, acc[4]);  acc[5]  = fmaf(w1.y, rv, acc[5]);
    acc[6]  = fmaf(w1.z, rv, acc[6]);  acc[7]  = fmaf(w1.w, rv, acc[7]);
    acc[8]  = fmaf(w2.x, rv, acc[8]);  acc[9]  = fmaf(w2.y, rv, acc[9]);
    acc[10] = fmaf(w2.z, rv, acc[10]); acc[11] = fmaf(w2.w, rv, acc[11]);
    acc[12] = fmaf(w3.x, rv, acc[12]); acc[13] = fmaf(w3.y, rv, acc[13]);
    acc[14] = fmaf(w3.z, rv, acc[14]); acc[15] = fmaf(w3.w, rv, acc[15]);
}

// 64 rows of each of two streams, 8-row blocks, double-buffered r prefetch
// (16 coherent loads in flight over each 256-FMA block to hide L3 latency).
__device__ __forceinline__ void gemm_seg(const float* __restrict__ rb1,
                                         const float* __restrict__ rb2,
                                         const float* __restrict__ wb1,
                                         const float* __restrict__ wb2,
                                         float acc[16]) {
    float a1[8], a2[8], b1[8], b2[8];
    #pragma unroll
    for (int i = 0; i < 8; ++i) { a1[i] = ld_cg(rb1 + i * 128); a2[i] = ld_cg(rb2 + i * 128); }
    #pragma unroll 1
    for (int jb = 0; jb < 8; jb += 2) {
        #pragma unroll
        for (int i = 0; i < 8; ++i) {
            int k = (jb + 1) * 8 + i;
            b1[i] = ld_cg(rb1 + k * 128); b2[i] = ld_cg(rb2 + k * 128);
        }
        #pragma unroll
        for (int i = 0; i < 8; ++i) {
            int k = jb * 8 + i;
            fma16(acc, wb1 + k * 512, a1[i]); fma16(acc, wb2 + k * 512, a2[i]);
        }
        int nb = (jb + 2 < 8) ? (jb + 2) : 0;  // clamped dummy prefetch on last iter
        #pragma unroll
        for (int i = 0; i < 8; ++i) {
            int k = nb * 8 + i;
            a1[i] = ld_cg(rb1 + k * 128); a2[i] = ld_cg(rb2 + k * 128);
        }
        #pragma unroll
        for (int i = 0; i < 8; ++i) {
            int k = (jb + 1) * 8 + i;
            fma16(acc, wb1 + k * 512, b1[i]); fma16(acc, wb2 + k * 512, b2[i]);
        }
    }
}

extern "C" __global__ void __launch_bounds__(NTHR)
rnn_kernel(const float* __restrict__ X,
           const float* __restrict__ Wra, const float* __restrict__ Wrb,
           const float* __restrict__ Wrc, const float* __restrict__ Wab,
           const float* __restrict__ Wbc, const float* __restrict__ Wca,
           const float* __restrict__ Wina, const float* __restrict__ Woutc,
           float* __restrict__ out, unsigned* __restrict__ ws) {
    const int tid = threadIdx.x;
    const int wg  = blockIdx.x;
    const int gid = wg * NTHR + tid;

    // ---------------- phase 0 (parallel): build layouts ----------------
    for (int i = gid; i < 3 * 1088 * 512; i += GTHREADS) {
        int R   = i / (1088 * 512);
        int rem = i - R * (1088 * 512);
        int k = rem >> 9, n = rem & 511;
        float v = 0.0f;
        if (R == 0) {
            if (k < 512)       v = Wra[n * 512 + k];
            else if (k < 1024) v = Wca[n * 512 + (k - 512)];
            else               v = Wina[n * 64 + (k - 1024)];
        } else if (R == 1) {
            if (k < 512)       v = Wrb[n * 512 + k];
            else if (k < 1024) v = Wab[n * 512 + (k - 512)];
        } else {
            if (k < 512)       v = Wrc[n * 512 + k];
            else if (k < 1024) v = Wbc[n * 512 + (k - 512)];
        }
        g_Wcat[R][k][n] = v;                     // normal store, published by fence
    }
    for (int i = gid; i < 511 * 64 * 128; i += GTHREADS) {
        int t   = i / (64 * 128) + 1;
        int rem = i & (64 * 128 - 1);
        int d = rem >> 7, b = rem & 127;
        g_XT[t][d][b] = X[(t * 128 + b) * 64 + d];
    }
    {   // r(t=0) zeros and out zeros go through the coherent path (write-through)
        float* r0 = &g_r[0][0][0][0];
        for (int i = gid; i < 3 * 512 * 128; i += GTHREADS) st_wt(&r0[i], 0.0f);
        for (int i = gid; i < 511 * 128 * 2; i += GTHREADS) st_wt(&out[i], 0.0f);
    }

    // ---------------- decomposition ----------------
    const int R    = wg >> 6;                 // 64 WGs per region
    const int cg   = (wg >> 1) & 31;
    const int bh   = wg & 1;
    const int n0   = cg * 16;
    const int b0   = bh * 64;
    const int w    = tid >> 6;                // wave 0..7 (NOT readfirstlane: keep
    const int lane = tid & 63;                // weight loads on the vector path)
    const int b    = b0 + lane;
    const int src2 = (R + 2) % 3;             // A<-C, B<-A, C<-B
    const int c_own = tid >> 5;               // owned col (2 outputs/thread)
    const int b_own = (tid * 2) & 63;         // owned batch pair
    float2 xq = make_float2(0.0f, 0.0f);      // persistent state in regs

    __shared__ float part[8][16][64];         // 32 KB K-split partials
    __shared__ float part2[16][64][2];        // 8 KB readout partials

    grid_barrier(ws, wg, 1u, true);           // ONLY fenced barrier (publish phase 0)

    for (int t = 1; t < 512; ++t) {
        const int prev = (t + 1) & 1, cur = t & 1;
        float acc[16];
        #pragma unroll
        for (int c = 0; c < 16; ++c) acc[c] = 0.0f;

        const float* rb1 = &g_r[prev][R][w * 64][0] + b;
        const float* rb2 = &g_r[prev][src2][w * 64][0] + b;
        const float* wb1 = &g_Wcat[R][w * 64][n0];
        const float* wb2 = &g_Wcat[R][512 + w * 64][n0];
        gemm_seg(rb1, rb2, wb1, wb2, acc);

        if (R == 0) {  // input projection: 8 rows/wave, XT is clean -> normal loads
            const float* rb3 = &g_XT[t][w * 8][0] + b;
            const float* wb3 = &g_Wcat[0][1024 + w * 8][n0];
            #pragma unroll
            for (int i = 0; i < 8; ++i) fma16(acc, wb3 + i * 512, rb3[i * 128]);
        }

        // ---- cross-wave K reduction (conflict-free: lane-contiguous writes) ----
        #pragma unroll
        for (int c = 0; c < 16; ++c) part[w][c][lane] = acc[c];
        __syncthreads();

        float2 s = make_float2(0.0f, 0.0f);
        #pragma unroll
        for (int ww = 0; ww < 8; ++ww) {
            float2 p = *(const float2*)&part[ww][c_own][b_own];
            s.x += p.x; s.y += p.y;
        }

        xq.x = 0.9f * xq.x + 0.1f * s.x;
        xq.y = 0.9f * xq.y + 0.1f * s.y;
        float2 r2 = make_float2(fast_tanh(xq.x), fast_tanh(xq.y));
        st_wt2(&g_r[cur][R][n0 + c_own][b0 + b_own], r2);   // write-through publish

        if (R == 2) {  // fused readout
            float w0 = Woutc[n0 + c_own];
            float w1 = Woutc[512 + n0 + c_own];
            part2[c_own][b_own + 0][0] = r2.x * w0; part2[c_own][b_own + 0][1] = r2.x * w1;
            part2[c_own][b_own + 1][0] = r2.y * w0; part2[c_own][b_own + 1][1] = r2.y * w1;
            __syncthreads();
            if (tid < 128) {
                int bb = tid >> 1, d = tid & 1;
                float ssum = 0.0f;
                #pragma unroll
                for (int c = 0; c < 16; ++c) ssum += part2[c][bb][d];
                atomicAdd(&out[(t - 1) * 256 + (b0 + bb) * 2 + d], ssum);
            }
        }

        if (t < 511) grid_barrier(ws, wg, (unsigned)(t + 1), false);  // fence-free
    }
}

extern "C" void kernel_launch(void* const* d_in, const int* in_sizes, int n_in,
                              void* d_out, int out_size, void* d_ws, size_t ws_size,
                              hipStream_t stream) {
    const float* X    = (const float*)d_in[0];
    const float* Wra  = (const float*)d_in[1];
    const float* Wrb  = (const float*)d_in[2];
    const float* Wrc  = (const float*)d_in[3];
    const float* Wab  = (const float*)d_in[4];
    const float* Wbc  = (const float*)d_in[5];
    const float* Wca  = (const float*)d_in[6];
    const float* Wina = (const float*)d_in[7];
    const float* Wout = (const float*)d_in[8];
    float* out = (float*)d_out;
    unsigned* ws = (unsigned*)d_ws;

    hipMemsetAsync(ws, 0, 8192, stream);  // counters + epoch flag

    void* args[] = { (void*)&X, (void*)&Wra, (void*)&Wrb, (void*)&Wrc,
                     (void*)&Wab, (void*)&Wbc, (void*)&Wca, (void*)&Wina,
                     (void*)&Wout, (void*)&out, (void*)&ws };
    hipLaunchCooperativeKernel((const void*)rnn_kernel, dim3(NWG), dim3(NTHR),
                               args, 0, stream);
}

// Round 3
// 6745.686 us; speedup vs baseline: 6.3978x; 6.3978x over previous
//
#include <hip/hip_runtime.h>

// MultiRegionRNN T=512,B=128,D_IN=64,N=512,D_OUT=2,ALPHA=0.1
// Persistent cooperative kernel, 511 steps, grid barrier per step.
// Round-3: (1) per-WG weight slice staged in LDS (broadcast ds_read_b128 in the
// hot loop, no global weight traffic), (2) 96-deep UC r-load pipelining,
// (3) no hot-loop atomics (readout partials -> g_po slab, reduced at the end),
// (4) relay barrier via RMW return values (no polling relay WG).

#define NWG   192
#define NTHR  512
#define GTHREADS (NWG * NTHR)
#define SMEM_FLOATS (1088*16 + 8*16*64 + 16*64*2)

__device__ float g_Wcat[3][1088][512];   // k-major weights [rec512|inter512|inA64]
__device__ float g_XT[512][64][128];     // transposed input
__device__ float g_r[2][3][512][128];    // ping-pong rates (coherent path)
__device__ float g_po[32][511][256];     // readout partials per col-group

__device__ __forceinline__ float fast_tanh(float x) {
    float e = __expf(2.0f * x);
    return 1.0f - 2.0f / (e + 1.0f);
}
// L2-bypass coherent load / write-through store (cross-XCD r exchange)
__device__ __forceinline__ float ld_cg(const float* p) {
    return __hip_atomic_load(p, __ATOMIC_RELAXED, __HIP_MEMORY_SCOPE_AGENT);
}
__device__ __forceinline__ void st_wt2(float* p, float2 v) {
    union { float2 f; unsigned long long u; } cv; cv.f = v;
    __hip_atomic_store((unsigned long long*)p, cv.u, __ATOMIC_RELAXED,
                       __HIP_MEMORY_SCOPE_AGENT);
}

// ws[i*64] i<16: group counters (12 WGs each); ws[1088]: super; ws[1024]: epoch flag
__device__ __forceinline__ void grid_barrier(unsigned* ws, int wg, unsigned epoch,
                                             bool full_fence) {
    asm volatile("s_waitcnt vmcnt(0)" ::: "memory");  // r/po stores acked
    __syncthreads();
    if (threadIdx.x == 0) {
        if (full_fence) __builtin_amdgcn_fence(__ATOMIC_RELEASE, "agent");
        unsigned old = __hip_atomic_fetch_add(&ws[(wg & 15) * 64], 1u,
                                              __ATOMIC_RELAXED, __HIP_MEMORY_SCOPE_AGENT);
        if (old + 1u == 12u * epoch) {             // last of my group this epoch
            unsigned o2 = __hip_atomic_fetch_add(&ws[1088], 1u,
                                                 __ATOMIC_RELAXED, __HIP_MEMORY_SCOPE_AGENT);
            if (o2 + 1u == 16u * epoch)            // last group overall
                __hip_atomic_store(&ws[1024], epoch, __ATOMIC_RELAXED,
                                   __HIP_MEMORY_SCOPE_AGENT);
        }
        while ((int)(__hip_atomic_load(&ws[1024], __ATOMIC_RELAXED,
                                       __HIP_MEMORY_SCOPE_AGENT) - epoch) < 0)
            __builtin_amdgcn_s_sleep(1);
        if (full_fence) __builtin_amdgcn_fence(__ATOMIC_ACQUIRE, "agent");
    }
    __syncthreads();
}

// 16 FMAs; wrow is a wave-uniform LDS row -> 4x broadcast ds_read_b128
__device__ __forceinline__ void fma16_lds(float acc[16], const float* wrow, float rv) {
    const float4* w4 = (const float4*)wrow;
    float4 w0 = w4[0], w1 = w4[1], w2 = w4[2], w3 = w4[3];
    acc[0]  = fmaf(w0.x, rv, acc[0]);  acc[1]  = fmaf(w0.y, rv, acc[1]);
    acc[2]  = fmaf(w0.z, rv, acc[2]);  acc[3]  = fmaf(w0.w, rv, acc[3]);
    acc[4]  = fmaf(w1.x, rv, acc[4]);  acc[5]  = fmaf(w1.y, rv, acc[5]);
    acc[6]  = fmaf(w1.z, rv, acc[6]);  acc[7]  = fmaf(w1.w, rv, acc[7]);
    acc[8]  = fmaf(w2.x, rv, acc[8]);  acc[9]  = fmaf(w2.y, rv, acc[9]);
    acc[10] = fmaf(w2.z, rv, acc[10]); acc[11] = fmaf(w2.w, rv, acc[11]);
    acc[12] = fmaf(w3.x, rv, acc[12]); acc[13] = fmaf(w3.y, rv, acc[13]);
    acc[14] = fmaf(w3.z, rv, acc[14]); acc[15] = fmaf(w3.w, rv, acc[15]);
}

#define LOADBLK(J, U, V) do {                                   \
    _Pragma("unroll")                                           \
    for (int i = 0; i < 16; ++i) {                              \
        U[i] = ld_cg(rb1 + ((J)*16 + i)*128);                   \
        V[i] = ld_cg(rb2 + ((J)*16 + i)*128);                   \
    } } while (0)
#define COMPBLK(J, U, V) do {                                   \
    _Pragma("unroll")                                           \
    for (int i = 0; i < 16; ++i) {                              \
        fma16_lds(acc, wl1 + ((J)*16 + i)*16, U[i]);            \
        fma16_lds(acc, wl2 + ((J)*16 + i)*16, V[i]);            \
    } } while (0)

extern "C" __global__ void __launch_bounds__(NTHR, 2)
rnn_kernel(const float* __restrict__ X,
           const float* __restrict__ Wra, const float* __restrict__ Wrb,
           const float* __restrict__ Wrc, const float* __restrict__ Wab,
           const float* __restrict__ Wbc, const float* __restrict__ Wca,
           const float* __restrict__ Wina, const float* __restrict__ Woutc,
           float* __restrict__ out, unsigned* __restrict__ ws) {
    extern __shared__ float smem[];
    float* Wl    = smem;                      // [1088][16] 68KB
    float* part  = smem + 1088 * 16;          // [8][16][64] 32KB
    float* part2 = part + 8 * 16 * 64;        // [16][64][2]  8KB

    const int tid = threadIdx.x;
    const int wg  = blockIdx.x;
    const int gid = wg * NTHR + tid;

    // ---------------- phase 0 (parallel): build layouts ----------------
    for (int i = gid; i < 3 * 1088 * 512; i += GTHREADS) {
        int R   = i / (1088 * 512);
        int rem = i - R * (1088 * 512);
        int k = rem >> 9, n = rem & 511;
        float v = 0.0f;
        if (R == 0) {
            if (k < 512)       v = Wra[n * 512 + k];
            else if (k < 1024) v = Wca[n * 512 + (k - 512)];
            else               v = Wina[n * 64 + (k - 1024)];
        } else if (R == 1) {
            if (k < 512)       v = Wrb[n * 512 + k];
            else if (k < 1024) v = Wab[n * 512 + (k - 512)];
        } else {
            if (k < 512)       v = Wrc[n * 512 + k];
            else if (k < 1024) v = Wbc[n * 512 + (k - 512)];
        }
        g_Wcat[R][k][n] = v;
    }
    for (int i = gid; i < 511 * 64 * 128; i += GTHREADS) {
        int t   = i / (64 * 128) + 1;
        int rem = i & (64 * 128 - 1);
        int d = rem >> 7, b = rem & 127;
        g_XT[t][d][b] = X[(t * 128 + b) * 64 + d];
    }
    // no r0 zeroing needed: t=1 skips r reads; buffer 0 is never read.

    // ---------------- decomposition ----------------
    const int R    = wg >> 6;                 // 64 WGs per region
    const int cg   = (wg >> 1) & 31;
    const int bh   = wg & 1;
    const int n0   = cg * 16;
    const int b0   = bh * 64;
    const int w    = tid >> 6;                // wave 0..7 (K-split)
    const int lane = tid & 63;
    const int b    = b0 + lane;
    const int src2 = (R + 2) % 3;             // A<-C, B<-A, C<-B
    const int c_own = tid >> 5;
    const int b_own = (tid * 2) & 63;
    float2 xq = make_float2(0.0f, 0.0f);
    const float wo0 = Woutc[n0 + c_own];          // readout weights (hoisted)
    const float wo1 = Woutc[512 + n0 + c_own];

    grid_barrier(ws, wg, 1u, true);           // publish phase 0 (full fences)

    // ---------------- stage weight slice into LDS (once) ----------------
    for (int i = tid; i < 1088 * 16; i += NTHR) {
        int k = i >> 4, nf = i & 15;
        Wl[i] = g_Wcat[R][k][n0 + nf];
    }
    __syncthreads();

    float rx[8];
    if (R == 0) {
        #pragma unroll
        for (int i = 0; i < 8; ++i) rx[i] = g_XT[1][w * 8 + i][b];
    }

    // ---------------- 511 sequential steps ----------------
    #pragma unroll 1
    for (int t = 1; t < 512; ++t) {
        const int prev = (t + 1) & 1, cur = t & 1;
        float acc[16];
        #pragma unroll
        for (int c = 0; c < 16; ++c) acc[c] = 0.0f;

        if (t > 1) {
            const float* rb1 = &g_r[prev][R][w * 64][0] + b;
            const float* rb2 = &g_r[prev][src2][w * 64][0] + b;
            const float* wl1 = Wl + (w * 64) * 16;
            const float* wl2 = Wl + (512 + w * 64) * 16;
            float rA1[16], rA2[16], rB1[16], rB2[16], rC1[16], rC2[16];
            LOADBLK(0, rA1, rA2);             // 96 coherent loads in flight
            LOADBLK(1, rB1, rB2);
            LOADBLK(2, rC1, rC2);
            COMPBLK(0, rA1, rA2);
            LOADBLK(3, rA1, rA2);             // rotate into A
            COMPBLK(1, rB1, rB2);
            COMPBLK(2, rC1, rC2);
            COMPBLK(3, rA1, rA2);
        }
        if (R == 0) {                         // input projection (XT prefetched)
            #pragma unroll
            for (int i = 0; i < 8; ++i)
                fma16_lds(acc, Wl + (1024 + w * 8 + i) * 16, rx[i]);
        }

        // ---- cross-wave K reduction ----
        #pragma unroll
        for (int c = 0; c < 16; ++c) part[(w * 16 + c) * 64 + lane] = acc[c];
        __syncthreads();
        float2 s = make_float2(0.0f, 0.0f);
        #pragma unroll
        for (int ww = 0; ww < 8; ++ww) {
            float2 p = *(const float2*)&part[(ww * 16 + c_own) * 64 + b_own];
            s.x += p.x; s.y += p.y;
        }

        xq.x = 0.9f * xq.x + 0.1f * s.x;
        xq.y = 0.9f * xq.y + 0.1f * s.y;
        float2 r2 = make_float2(fast_tanh(xq.x), fast_tanh(xq.y));
        st_wt2(&g_r[cur][R][n0 + c_own][b0 + b_own], r2);   // coherent publish

        if (R == 2) {                         // readout partial -> private slab
            float* p2 = part2 + (c_own * 64 + b_own) * 2;
            p2[0] = r2.x * wo0; p2[1] = r2.x * wo1;
            p2[2] = r2.y * wo0; p2[3] = r2.y * wo1;
            __syncthreads();
            if (tid < 128) {
                int bb = tid >> 1, d = tid & 1;
                float ssum = 0.0f;
                #pragma unroll
                for (int c = 0; c < 16; ++c) ssum += part2[(c * 64 + bb) * 2 + d];
                g_po[cg][t - 1][(b0 + bb) * 2 + d] = ssum;   // plain store, no atomic
            }
        }
        if (R == 0 && t < 511) {              // prefetch next step's input
            #pragma unroll
            for (int i = 0; i < 8; ++i) rx[i] = g_XT[t + 1][w * 8 + i][b];
        }

        if (t < 511) grid_barrier(ws, wg, (unsigned)(t + 1), false);
    }

    grid_barrier(ws, wg, 512u, true);         // publish g_po (full fences)

    // ---------------- final readout reduction (parallel) ----------------
    for (int i = gid; i < 511 * 256; i += GTHREADS) {
        int t = i >> 8, rem = i & 255;
        float ssum = 0.0f;
        #pragma unroll
        for (int cgi = 0; cgi < 32; ++cgi) ssum += g_po[cgi][t][rem];
        out[i] = ssum;
    }
}

extern "C" void kernel_launch(void* const* d_in, const int* in_sizes, int n_in,
                              void* d_out, int out_size, void* d_ws, size_t ws_size,
                              hipStream_t stream) {
    const float* X    = (const float*)d_in[0];
    const float* Wra  = (const float*)d_in[1];
    const float* Wrb  = (const float*)d_in[2];
    const float* Wrc  = (const float*)d_in[3];
    const float* Wab  = (const float*)d_in[4];
    const float* Wbc  = (const float*)d_in[5];
    const float* Wca  = (const float*)d_in[6];
    const float* Wina = (const float*)d_in[7];
    const float* Wout = (const float*)d_in[8];
    float* out = (float*)d_out;
    unsigned* ws = (unsigned*)d_ws;

    hipMemsetAsync(ws, 0, 8192, stream);      // barrier counters + flags

    hipFuncSetAttribute((const void*)rnn_kernel,
                        hipFuncAttributeMaxDynamicSharedMemorySize,
                        SMEM_FLOATS * sizeof(float));

    void* args[] = { (void*)&X, (void*)&Wra, (void*)&Wrb, (void*)&Wrc,
                     (void*)&Wab, (void*)&Wbc, (void*)&Wca, (void*)&Wina,
                     (void*)&Wout, (void*)&out, (void*)&ws };
    hipLaunchCooperativeKernel((const void*)rnn_kernel, dim3(NWG), dim3(NTHR),
                               args, SMEM_FLOATS * sizeof(float), stream);
}